// Round 3
// baseline (181.956 us; speedup 1.0000x reference)
//
#include <hip/hip_runtime.h>
#include <math.h>

#define NREL  32
#define NENT  2048
#define NATTR 8
#define WIDTH 256
#define NK    (2 * NREL + NATTR)   // 72
#define CHUNKS 64
#define ROWS  (NENT / CHUNKS)      // 32 rows per block

// ---------------------------------------------------------------------------
// Kernel A: one pass over database. Block = (relation r, 32-row chunk).
// Wave w owns the 512-column slice [512w, 512w+512) of ALL 32 rows:
//   - column partials: acc of 2 float4/lane, complete in-wave -> direct
//     coalesced write to partial[bx][512w..] (no 32KB LDS combine).
//   - row sums: per-lane 8-float sum, paired 64->1 butterfly, 4 wave-slices
//     combined via 512B LDS -> quantified[32+r][..].
// 2048 blocks, low VGPR, tiny LDS -> max occupancy.
// ---------------------------------------------------------------------------
__global__ __launch_bounds__(256) void reduce_db_kernel(
    const float* __restrict__ db,
    float* __restrict__ qout,        // quantified region [72][2048]
    float* __restrict__ partial)     // [NREL*CHUNKS][2048]
{
    const int bx    = blockIdx.x;
    const int r     = bx >> 6;             // / CHUNKS
    const int chunk = bx & (CHUNKS - 1);
    const int tid   = threadIdx.x;
    const int wave  = tid >> 6;
    const int lane  = tid & 63;
    const int i0    = chunk * ROWS;

    // float4 pointer to this wave's slice of the chunk's first row
    const float4* base = reinterpret_cast<const float4*>(db)
                       + (size_t)r * NENT * (NENT / 4)
                       + (size_t)i0 * (NENT / 4)
                       + wave * 128 + lane;

    float4 acc0 = make_float4(0.f, 0.f, 0.f, 0.f);
    float4 acc1 = make_float4(0.f, 0.f, 0.f, 0.f);

    __shared__ float rsum[ROWS][4];

    for (int j = 0; j < ROWS; j += 2) {
        const float4* rowA = base + (size_t)j * (NENT / 4);
        const float4* rowB = rowA + (NENT / 4);
        float4 a0 = rowA[0];
        float4 a1 = rowA[64];
        float4 b0 = rowB[0];
        float4 b1 = rowB[64];

        acc0.x += a0.x; acc0.y += a0.y; acc0.z += a0.z; acc0.w += a0.w;
        acc1.x += a1.x; acc1.y += a1.y; acc1.z += a1.z; acc1.w += a1.w;
        float rsA = ((a0.x + a0.y) + (a0.z + a0.w)) +
                    ((a1.x + a1.y) + (a1.z + a1.w));

        acc0.x += b0.x; acc0.y += b0.y; acc0.z += b0.z; acc0.w += b0.w;
        acc1.x += b1.x; acc1.y += b1.y; acc1.z += b1.z; acc1.w += b1.w;
        float rsB = ((b0.x + b0.y) + (b0.z + b0.w)) +
                    ((b1.x + b1.y) + (b1.z + b1.w));

        // paired reduction: fold 64->32 both rows, select, 5-step butterfly
        rsA += __shfl_xor(rsA, 32, 64);
        rsB += __shfl_xor(rsB, 32, 64);
        float c = (lane < 32) ? rsA : rsB;
#pragma unroll
        for (int off = 16; off > 0; off >>= 1)
            c += __shfl_xor(c, off, 64);
        if ((lane & 31) == 0)
            rsum[j + (lane >> 5)][wave] = c;   // slice sum for this wave
    }
    __syncthreads();

    if (tid < ROWS) {
        float s = (rsum[tid][0] + rsum[tid][1]) +
                  (rsum[tid][2] + rsum[tid][3]);
        qout[(size_t)(NREL + r) * NENT + i0 + tid] = 1.f - __expf(-s);
    }

    // direct per-wave column-partial write (coalesced 1KB segments)
    float4* p4 = reinterpret_cast<float4*>(partial)
               + (size_t)bx * (NENT / 4) + wave * 128 + lane;
    p4[0]  = acc0;
    p4[64] = acc1;
}

// ---------------------------------------------------------------------------
// Kernel B (merged): blocks 0..319 finalize column sums (fully-unrolled
// 64 independent chunk loads) + attribute rows; block 320 does the weights
// softmax with fully-unrolled independent loads.
// ---------------------------------------------------------------------------
#define FIN_BLOCKS ((NREL + NATTR) * NENT / 256)   // 320

__global__ __launch_bounds__(256) void finalize_softmax_kernel(
    const float* __restrict__ partial,
    const float* __restrict__ attrs,
    const float* __restrict__ W,
    float* __restrict__ qout,
    float* __restrict__ sw)
{
    const int b = blockIdx.x;
    if (b < FIN_BLOCKS) {
        const int idx = b * 256 + threadIdx.x;   // over (32+8)*2048
        const int row = idx >> 11;
        const int n   = idx & (NENT - 1);
        if (row < NREL) {
            float s = 0.f;
#pragma unroll
            for (int c = 0; c < CHUNKS; ++c)     // compile-time: 64 indep loads
                s += partial[((size_t)(row * CHUNKS + c) << 11) + n];
            qout[((size_t)row << 11) + n] = 1.f - __expf(-s);
        } else {
            const int a = row - NREL;
            float v = attrs[((size_t)a << 11) + n];
            qout[((size_t)(2 * NREL + a) << 11) + n] = 1.f - __expf(-2.f * v);
        }
    } else {
        // softmax over the 72 rows of weights, per output column w
        const int w = threadIdx.x;  // 0..255
        float v[NK];
#pragma unroll
        for (int k = 0; k < NK; ++k) v[k] = W[k * WIDTH + w];  // 72 indep loads
        float m = v[0];
#pragma unroll
        for (int k = 1; k < NK; ++k) m = fmaxf(m, v[k]);
        float s = 0.f;
#pragma unroll
        for (int k = 0; k < NK; ++k) { v[k] = __expf(v[k] - m); s += v[k]; }
        const float inv = 1.f / s;
#pragma unroll
        for (int k = 0; k < NK; ++k) sw[k * WIDTH + w] = v[k] * inv;
    }
}

// ---------------------------------------------------------------------------
// Kernel C: outputs[w][n] = sum_k sw[k][w] * quantified[k][n].
// 2 blocks per w (512 blocks); sw column staged in LDS (broadcast reads);
// 1 float4 per thread; quant is L2-resident.
// ---------------------------------------------------------------------------
__global__ __launch_bounds__(256) void matmul_kernel(
    const float* __restrict__ sw,
    const float* __restrict__ quant,
    float* __restrict__ out)
{
    const int w = blockIdx.x >> 1;                           // 0..255
    const int g = (blockIdx.x & 1) * 256 + threadIdx.x;      // float4 col

    __shared__ float sWcol[NK];
    if (threadIdx.x < NK) sWcol[threadIdx.x] = sw[threadIdx.x * WIDTH + w];
    __syncthreads();

    const float4* q4 = reinterpret_cast<const float4*>(quant);
    float4 a = make_float4(0.f, 0.f, 0.f, 0.f);
#pragma unroll 8
    for (int k = 0; k < NK; ++k) {
        const float s = sWcol[k];
        float4 v = q4[k * (NENT / 4) + g];
        a.x += s * v.x; a.y += s * v.y; a.z += s * v.z; a.w += s * v.w;
    }
    reinterpret_cast<float4*>(out)[(size_t)w * (NENT / 4) + g] = a;
}

extern "C" void kernel_launch(void* const* d_in, const int* in_sizes, int n_in,
                              void* d_out, int out_size, void* d_ws, size_t ws_size,
                              hipStream_t stream)
{
    const float* db    = (const float*)d_in[0];  // [32][2048][2048]
    const float* attrs = (const float*)d_in[1];  // [8][2048]
    const float* W     = (const float*)d_in[2];  // [72][256]

    float* out   = (float*)d_out;                    // [256][2048]
    float* quant = out + (size_t)WIDTH * NENT;       // [72][2048]

    float* partial = (float*)d_ws;                             // [32*64][2048]
    float* sw      = partial + (size_t)NREL * CHUNKS * NENT;   // [72][256]

    reduce_db_kernel<<<NREL * CHUNKS, 256, 0, stream>>>(db, quant, partial);
    finalize_softmax_kernel<<<FIN_BLOCKS + 1, 256, 0, stream>>>(
        partial, attrs, W, quant, sw);
    matmul_kernel<<<WIDTH * 2, 256, 0, stream>>>(sw, quant, out);
}